// Round 2
// 653.084 us; speedup vs baseline: 3.5727x; 3.5727x over previous
//
#include <hip/hip_runtime.h>

typedef float v2f __attribute__((ext_vector_type(2)));
typedef float v4f __attribute__((ext_vector_type(4)));

static __device__ __forceinline__ v2f fma2(v2f a, v2f b, v2f c) {
    return __builtin_elementwise_fma(a, b, c);
}

// Problem constants
// x1: (32768, 16, 64), x2: (32768, 16, 32), w: (32768, 64, 32)
// A,B,C: (16, 64); out: (32768, 16, 64)
//
// Algebraic reorder vs reference:
//   t3[r,o] = sum_v t2[r,v] w[o,v] = sum_j B[j,r] * q[j,o],
//   q[j,o]  = sum_v x2[j,v] w[o,v]
// -> q is 16 scalars per lane (lane=o); no t2 LDS buffer, 22% fewer FLOPs.
constexpr int ITERS = 4;  // batches per wave

__global__ __launch_bounds__(256, 3)
void cp_tp_kernel(const float* __restrict__ x1g, const float* __restrict__ x2g,
                  const float* __restrict__ wg,  const float* __restrict__ Ag,
                  const float* __restrict__ Bg,  const float* __restrict__ Cg,
                  float* __restrict__ outg)
{
    // Batch-invariant operands, staged once. All fused-loop reads are
    // wave-uniform addresses -> LDS broadcast, conflict-free.
    __shared__ __align__(16) float A_s[16 * 64];   // [i][r] row-major
    __shared__ __align__(16) float Bt_s[64 * 16];  // [r][j] (B transposed)
    __shared__ __align__(16) float Ct_s[64 * 16];  // [r][c] (C transposed)
    __shared__ __align__(16) float x2_s[4][16 * 32];  // per-wave x2 tile

    const int tid  = threadIdx.x;
    const int wv   = tid >> 6;
    const int lane = tid & 63;

    for (int k = tid; k < 1024; k += 256) {
        A_s[k] = Ag[k];
        int row = k >> 6, col = k & 63;      // row = j or c, col = r
        Bt_s[col * 16 + row] = Bg[k];
        Ct_s[col * 16 + row] = Cg[k];
    }
    __syncthreads();  // the only barrier: A_s/Bt_s/Ct_s staged cooperatively

    for (int it = 0; it < ITERS; ++it) {
        const int b = (blockIdx.x * ITERS + it) * 4 + wv;
        const float* x1b = x1g + (size_t)b * 1024;
        const float* x2b = x2g + (size_t)b * 512;
        const float* wb  = wg  + (size_t)b * 2048;

        // ---- stage x2 tile into this wave's private LDS slab ----
        // (per-wave buffer: wave-internal ds ordering via lgkmcnt suffices,
        //  no block barrier needed)
        {
            const v4f* src = (const v4f*)x2b;
            v4f* dst = (v4f*)x2_s[wv];
            dst[lane]      = src[lane];
            dst[lane + 64] = src[lane + 64];
        }

        // ---- issue x1 column loads early (latency hiding) ----
        float xr[16];
#pragma unroll
        for (int i = 0; i < 16; ++i) xr[i] = x1b[i * 64 + lane];

        // ---- w row for this lane: w[b][lane][0..31] ----
        v4f wq[8];
        {
            const v4f* wp = (const v4f*)(wb + lane * 32);
#pragma unroll
            for (int k = 0; k < 8; ++k) wq[k] = wp[k];
        }

        // ---- q[j] = sum_v x2[j,v] * w[lane,v], packed as v2f[8] ----
        v2f q2[8];
#pragma unroll
        for (int jp = 0; jp < 8; ++jp) {
            v2f acc0 = v2f{0.f, 0.f}, acc1 = v2f{0.f, 0.f};
            const v4f* xrow0 = (const v4f*)(x2_s[wv] + (2 * jp) * 32);
            const v4f* xrow1 = (const v4f*)(x2_s[wv] + (2 * jp + 1) * 32);
#pragma unroll
            for (int k = 0; k < 8; ++k) {
                v4f xq0 = xrow0[k], xq1 = xrow1[k];
                v2f wlo = {wq[k].x, wq[k].y}, whi = {wq[k].z, wq[k].w};
                acc0 = fma2(v2f{xq0.x, xq0.y}, wlo, acc0);
                acc0 = fma2(v2f{xq0.z, xq0.w}, whi, acc0);
                acc1 = fma2(v2f{xq1.x, xq1.y}, wlo, acc1);
                acc1 = fma2(v2f{xq1.z, xq1.w}, whi, acc1);
            }
            q2[jp] = v2f{acc0.x + acc0.y, acc1.x + acc1.y};
        }
        // wq dead from here -> frees 32 VGPRs before t1v goes live

        // ---- t1[r] = sum_i x1[i,lane] * A[i,r], 32 x v2f ----
        v2f t1v[32];
#pragma unroll
        for (int rp = 0; rp < 32; ++rp) t1v[rp] = v2f{0.f, 0.f};
#pragma unroll
        for (int i = 0; i < 16; ++i) {
            v2f xv = {xr[i], xr[i]};
            const v4f* arow = (const v4f*)(A_s + i * 64);
#pragma unroll
            for (int r4 = 0; r4 < 16; ++r4) {
                v4f a4 = arow[r4];
                t1v[2 * r4]     = fma2(xv, v2f{a4.x, a4.y}, t1v[2 * r4]);
                t1v[2 * r4 + 1] = fma2(xv, v2f{a4.z, a4.w}, t1v[2 * r4 + 1]);
            }
        }
        // xr dead from here

        // ---- fused: per r: t3 = Bt[r]·q; p = t1[r]*t3; out += p*Ct[r] ----
        // Live set: t1v(64) + q2(16) + outv(16) ~= 96 VGPR + temps -> no spill
        v2f outv[8];
#pragma unroll
        for (int cp = 0; cp < 8; ++cp) outv[cp] = v2f{0.f, 0.f};

#pragma unroll
        for (int r = 0; r < 64; ++r) {
            const v4f* btr = (const v4f*)(Bt_s + r * 16);
            v2f acc = v2f{0.f, 0.f};
#pragma unroll
            for (int p4 = 0; p4 < 4; ++p4) {
                v4f b4 = btr[p4];
                acc = fma2(v2f{b4.x, b4.y}, q2[2 * p4], acc);
                acc = fma2(v2f{b4.z, b4.w}, q2[2 * p4 + 1], acc);
            }
            float t3  = acc.x + acc.y;
            float t1r = (r & 1) ? t1v[r >> 1].y : t1v[r >> 1].x;
            float p   = t1r * t3;
            v2f pv = {p, p};
            const v4f* ctr = (const v4f*)(Ct_s + r * 16);
#pragma unroll
            for (int c4 = 0; c4 < 4; ++c4) {
                v4f cq = ctr[c4];
                outv[2 * c4]     = fma2(pv, v2f{cq.x, cq.y}, outv[2 * c4]);
                outv[2 * c4 + 1] = fma2(pv, v2f{cq.z, cq.w}, outv[2 * c4 + 1]);
            }
        }

        // ---- store out[b, c, lane] (coalesced per c) ----
        float* ob = outg + (size_t)b * 1024;
#pragma unroll
        for (int c = 0; c < 16; ++c) {
            float v = (c & 1) ? outv[c >> 1].y : outv[c >> 1].x;
            ob[c * 64 + lane] = v;
        }
        // no barrier: x2_s[wv] is wave-private; per-wave LDS ops are in-order
    }
}

extern "C" void kernel_launch(void* const* d_in, const int* in_sizes, int n_in,
                              void* d_out, int out_size, void* d_ws, size_t ws_size,
                              hipStream_t stream) {
    const float* x1 = (const float*)d_in[0];
    const float* x2 = (const float*)d_in[1];
    const float* w  = (const float*)d_in[2];
    const float* A  = (const float*)d_in[3];
    const float* B  = (const float*)d_in[4];
    const float* C  = (const float*)d_in[5];
    float* out = (float*)d_out;

    // 2048 blocks * 4 iters * 4 waves/block = 32768 batches
    cp_tp_kernel<<<dim3(2048), dim3(256), 0, stream>>>(x1, x2, w, A, B, C, out);
}